// Round 20
// baseline (223.516 us; speedup 1.0000x reference)
//
#include <hip/hip_runtime.h>
#include <hip/hip_bf16.h>
#include <math.h>

#define EPSV 1e-4f
#define WA 0.91914503f          // 0.7 / sqrt(0.58)
#define WB 0.39392215f          // 0.3 / sqrt(0.58)
#define INV596 1.6778523f       // 1/0.596

typedef __bf16 bf16x8 __attribute__((ext_vector_type(8)));
typedef short  s16x8  __attribute__((ext_vector_type(8)));
typedef float  f32x4  __attribute__((ext_vector_type(4)));
typedef _Float16 f16x8 __attribute__((ext_vector_type(8)));

__device__ inline bf16x8 bzero8() { s16x8 z = 0; return __builtin_bit_cast(bf16x8, z); }

__device__ inline void store_bf4(__hip_bfloat16* p, float a, float b, float c, float d) {
    __hip_bfloat16 t[4];
    t[0] = __float2bfloat16(a); t[1] = __float2bfloat16(b);
    t[2] = __float2bfloat16(c); t[3] = __float2bfloat16(d);
    *(short4*)p = *(short4*)t;
}

__device__ inline void store_f16x4(_Float16* p, float a, float b, float c, float d) {
    _Float16 t[4];
    t[0] = (_Float16)a; t[1] = (_Float16)b; t[2] = (_Float16)c; t[3] = (_Float16)d;
    *(uint2*)p = *(uint2*)t;
}

// ---------------- prep: all weight norms + emb->c + pixnorm, one dispatch ----------------
__global__ __launch_bounds__(256) void prep_all(
        const float* __restrict__ x, const float* __restrict__ emb,
        const float* __restrict__ w_res0, const float* __restrict__ w_res1,
        const float* __restrict__ w_qkv, const float* __restrict__ w_proj,
        const float* __restrict__ w_emb, const float* __restrict__ emb_gain,
        __hip_bfloat16* __restrict__ W0B, __hip_bfloat16* __restrict__ W1B,
        __hip_bfloat16* __restrict__ WQB, __hip_bfloat16* __restrict__ WPB,
        float* __restrict__ CC, float* __restrict__ Xn,
        __hip_bfloat16* __restrict__ Ah) {
    __shared__ float sdata[4];
    int b = blockIdx.x;
    int tid = threadIdx.x;
    int wid = tid >> 6, lane = tid & 63;

    if (b < 512) {                       // 3x3 conv weight norm
        int oc = b & 255;
        const float* row = ((b < 256) ? w_res0 : w_res1) + (size_t)oc * 2304;
        __hip_bfloat16* wb = (b < 256) ? W0B : W1B;
        float ss = 0.f;
        for (int i = tid; i < 2304; i += 256) { float v = row[i]; ss += v * v; }
#pragma unroll
        for (int m = 32; m >= 1; m >>= 1) ss += __shfl_xor(ss, m);
        if (lane == 0) sdata[wid] = ss;
        __syncthreads();
        float tot = sdata[0] + sdata[1] + sdata[2] + sdata[3];
        float s = (1.0f / 48.0f) / (EPSV + sqrtf(tot) * (1.0f / 48.0f));
        for (int i = tid; i < 2304; i += 256) {
            int ic = i / 9, tap = i - ic * 9;
            wb[((size_t)tap * 256 + oc) * 256 + ic] = __float2bfloat16(row[i] * s);
        }
    } else if (b < 1536) {               // 1x1 conv weight norm (qkv permuted / proj)
        bool isq = (b < 1280);
        int oc = isq ? (b - 512) : (b - 1280);
        const float* row = (isq ? w_qkv : w_proj) + (size_t)oc * 256;
        float v0 = row[tid];
        float ss = v0 * v0;
#pragma unroll
        for (int m = 32; m >= 1; m >>= 1) ss += __shfl_xor(ss, m);
        if (lane == 0) sdata[wid] = ss;
        __syncthreads();
        float tot = sdata[0] + sdata[1] + sdata[2] + sdata[3];
        float s = 0.0625f / (EPSV + sqrtf(tot) * 0.0625f);
        if (isq) {
            int h = oc / 192, rem = oc - h * 192;
            int c = rem / 3, t = rem - c * 3;
            int newoc = t * 256 + h * 64 + c;
            WQB[(size_t)newoc * 256 + tid] = __float2bfloat16(v0 * s);
        } else {
            WPB[(size_t)oc * 256 + tid] = __float2bfloat16(v0 * s);
        }
    } else if (b < 1792) {               // emb weight row r: norm + c[n][r] directly
        int r = b - 1536;
        const float* row = w_emb + (size_t)r * 768;
        float ss = 0.f;
        for (int i = tid; i < 768; i += 256) { float v = row[i]; ss += v * v; }
#pragma unroll
        for (int m = 32; m >= 1; m >>= 1) ss += __shfl_xor(ss, m);
        if (lane == 0) sdata[wid] = ss;
        __syncthreads();
        float tot = sdata[0] + sdata[1] + sdata[2] + sdata[3];
        float g = emb_gain[0];
        float s = g * 0.036084392f / (EPSV + sqrtf(tot) * 0.036084392f);
        __shared__ float rowS[768];
        for (int i = tid; i < 768; i += 256) rowS[i] = row[i] * s;
        __syncthreads();
        int n_ = tid >> 3, k0 = tid & 7;
        float p = 0.f;
        for (int k = k0; k < 768; k += 8) p += emb[n_ * 768 + k] * rowS[k];
        p += __shfl_xor(p, 1);
        p += __shfl_xor(p, 2);
        p += __shfl_xor(p, 4);
        if (k0 == 0) CC[n_ * 256 + r] = p + 1.0f;
    } else {                             // pixnorm
        int idx = b - 1792;
        int n = idx >> 5;
        int sp = (idx & 31) * 32 + (tid & 31);
        int cg = tid >> 5;
        const float* xb = x + (size_t)n * 262144 + ((size_t)cg << 15) + sp;
        float v[32];
        float ss = 0.f;
#pragma unroll
        for (int i = 0; i < 32; i++) {
            v[i] = xb[(size_t)i << 10];
            ss += v[i] * v[i];
        }
        __shared__ float red[8][33];
        red[cg][tid & 31] = ss;
        __syncthreads();
        float tot = 0.f;
#pragma unroll
        for (int j = 0; j < 8; j++) tot += red[j][tid & 31];
        float inv = 1.0f / (EPSV + sqrtf(tot) * 0.0625f);
        float* xo = Xn + ((size_t)n * 1024 + sp) * 256 + cg * 32;
        __hip_bfloat16* ao = Ah + ((size_t)n * 1024 + sp) * 256 + cg * 32;
#pragma unroll
        for (int i = 0; i < 32; i += 4) {
            float a0 = v[i] * inv, a1 = v[i+1] * inv, a2 = v[i+2] * inv, a3 = v[i+3] * inv;
            *(float4*)&xo[i] = make_float4(a0, a1, a2, a3);
            float s0 = a0 / (1.0f + __expf(-a0)) * INV596;
            float s1 = a1 / (1.0f + __expf(-a1)) * INV596;
            float s2 = a2 / (1.0f + __expf(-a2)) * INV596;
            float s3 = a3 / (1.0f + __expf(-a3)) * INV596;
            store_bf4(&ao[i], s0, s1, s2, s3);
        }
    }
}

// ---------------- MFMA implicit-GEMM conv v6: 512 thr, full dbuf, ONE barrier/iter ----------
// Block = 64 oc x 512 sp (16 rows), 8 waves. X and W both double-buffered in
// swizzled LDS (KS=3: 152KB -> 1 blk/CU; KS=1: 73.7KB -> 2 blk/CU). Loop:
// issue loads(ch+1) -> compute(cur) -> write(cur^1) -> single barrier.
template<int KS, int ORI, int EPI, int GX>
__global__ __launch_bounds__(512) void convmfma(
        const __hip_bfloat16* __restrict__ xin,
        const __hip_bfloat16* __restrict__ wb,
        __hip_bfloat16* __restrict__ out_h,
        float* __restrict__ out_f,
        const float* __restrict__ xres,
        _Float16* __restrict__ vt_out,
        const float* __restrict__ cvec,
        int Cin, int Cout) {
    constexpr int TAPS = KS * KS;
    constexpr int RRD = 16 + KS - 1;      // 18 / 16
    constexpr int CCD = 32 + KS - 1;      // 34 / 32
    constexpr int HLO = KS / 2;
    constexpr int XSLOT = RRD * 128;      // 2304 / 2048
    constexpr int WSLOT = TAPS * 256;     // 2304 / 256
    constexpr int NXU = (XSLOT + 511) / 512;   // 5 / 4
    constexpr int NWU = (WSLOT + 511) / 512;   // 5 / 1
    __shared__ __align__(16) __hip_bfloat16 Xl[2][RRD * CCD * 32];
    __shared__ __align__(16) __hip_bfloat16 Wl[2][TAPS * 64 * 32];

    auto xoff = [](int rr, int cc, int gran) {
        int rowl = rr * CCD + cc;
        return rowl * 32 + ((gran ^ ((rowl >> 1) & 3)) << 3);
    };
    auto woff = [](int tap, int oc, int gran) {
        int rowl = tap * 64 + oc;
        return rowl * 32 + ((gran ^ ((rowl >> 1) & 3)) << 3);
    };

    // T1 XCD swizzle: GX oc-blocks share one (spb,n) input tile -> same XCD.
    int lin = blockIdx.x + GX * (blockIdx.y + 2 * blockIdx.z);
    constexpr int NBLK = GX * 2 * 32;
    constexpr int CPX = NBLK >> 3;              // 32 (GX=4) / 96 (GX=12): GX | CPX
    int swz = (lin & 7) * CPX + (lin >> 3);
    int oc0 = (swz % GX) * 64;
    int Wq = swz / GX;
    int spb = Wq & 1;
    int n = Wq >> 1;

    int tid = threadIdx.x;
    int r0 = spb * 16;
    int lane = tid & 63, wv = tid >> 6;         // wv 0..7
    int l15 = lane & 15, g = lane >> 4;

    // zero halo columns in both buffers once
    if (KS == 3) {
        if (tid < RRD * 8) {
            int rr = tid >> 3;
            int side = (tid >> 2) & 1;
            int slot = tid & 3;
            *(bf16x8*)&Xl[0][xoff(rr, side ? (CCD - 1) : 0, slot)] = bzero8();
            *(bf16x8*)&Xl[1][xoff(rr, side ? (CCD - 1) : 0, slot)] = bzero8();
        }
    }

    bf16x8 xp[NXU];
    bf16x8 wpf[NWU];
    auto loadX = [&](int ch) {
#pragma unroll
        for (int u = 0; u < NXU; u++) {
            int f = tid + u * 512;
            if (f < XSLOT) {
                int rr = f >> 7, rem = f & 127;
                int cc = rem >> 2, slot = rem & 3;
                int gr = r0 + rr - HLO;
                bf16x8 v = bzero8();
                if ((unsigned)gr < 32u)
                    v = *(const bf16x8*)&xin[((size_t)n * 1024 + gr * 32 + cc) * Cin + ch * 32 + slot * 8];
                xp[u] = v;
            }
        }
    };
    auto writeX = [&](int buf) {
#pragma unroll
        for (int u = 0; u < NXU; u++) {
            int f = tid + u * 512;
            if (f < XSLOT) {
                int rr = f >> 7, rem = f & 127;
                int cc = rem >> 2, slot = rem & 3;
                *(bf16x8*)&Xl[buf][xoff(rr, cc + HLO, slot)] = xp[u];
            }
        }
    };
    auto loadW = [&](int ch) {
#pragma unroll
        for (int u = 0; u < NWU; u++) {
            int f = tid + u * 512;
            if (f < WSLOT) {
                int tap = f >> 8, rem = f & 255;
                int oc = rem >> 2, slot = rem & 3;
                wpf[u] = *(const bf16x8*)&wb[((size_t)tap * Cout + oc0 + oc) * Cin + ch * 32 + slot * 8];
            }
        }
    };
    auto writeW = [&](int buf) {
#pragma unroll
        for (int u = 0; u < NWU; u++) {
            int f = tid + u * 512;
            if (f < WSLOT) {
                int tap = f >> 8, rem = f & 255;
                int oc = rem >> 2, slot = rem & 3;
                *(bf16x8*)&Wl[buf][woff(tap, oc, slot)] = wpf[u];
            }
        }
    };

    f32x4 acc[4][4];
    const f32x4 z4 = {0.f, 0.f, 0.f, 0.f};
#pragma unroll
    for (int a = 0; a < 4; a++)
#pragma unroll
        for (int b = 0; b < 4; b++) acc[a][b] = z4;

    int nch = Cin >> 5;
    loadX(0); loadW(0);
    writeX(0); writeW(0);
    __syncthreads();

    int cur = 0;
    for (int ch = 0; ch < nch; ++ch) {
        bool pf = (ch + 1 < nch);
        if (pf) { loadX(ch + 1); loadW(ch + 1); }   // global->regs; covered by compute
        if constexpr (KS == 3) {
#pragma unroll
            for (int dx = 0; dx < 3; dx++) {
                bf16x8 xv[4][2];
#pragma unroll
                for (int r = 0; r < 4; r++)
#pragma unroll
                    for (int b = 0; b < 2; b++)
                        xv[r][b] = *(const bf16x8*)&Xl[cur][xoff(2 * wv + r, b * 16 + l15 + dx, g)];
#pragma unroll
                for (int dy = 0; dy < 3; dy++) {
                    int tap = dy * 3 + dx;
                    bf16x8 af[4];
#pragma unroll
                    for (int of = 0; of < 4; of++)
                        af[of] = *(const bf16x8*)&Wl[cur][woff(tap, of * 16 + l15, g)];
#pragma unroll
                    for (int of = 0; of < 4; of++)
#pragma unroll
                        for (int sf = 0; sf < 4; sf++) {
                            if (ORI == 1)
                                acc[of][sf] = __builtin_amdgcn_mfma_f32_16x16x32_bf16(af[of], xv[(sf >> 1) + dy][sf & 1], acc[of][sf], 0, 0, 0);
                            else
                                acc[of][sf] = __builtin_amdgcn_mfma_f32_16x16x32_bf16(xv[(sf >> 1) + dy][sf & 1], af[of], acc[of][sf], 0, 0, 0);
                        }
                }
            }
        } else {
            bf16x8 af[4], bfv[4];
#pragma unroll
            for (int of = 0; of < 4; of++)
                af[of] = *(const bf16x8*)&Wl[cur][woff(0, of * 16 + l15, g)];
#pragma unroll
            for (int sf = 0; sf < 4; sf++)
                bfv[sf] = *(const bf16x8*)&Xl[cur][xoff(2 * wv + (sf >> 1), (sf & 1) * 16 + l15, g)];
#pragma unroll
            for (int of = 0; of < 4; of++)
#pragma unroll
                for (int sf = 0; sf < 4; sf++) {
                    if (ORI == 1)
                        acc[of][sf] = __builtin_amdgcn_mfma_f32_16x16x32_bf16(af[of], bfv[sf], acc[of][sf], 0, 0, 0);
                    else
                        acc[of][sf] = __builtin_amdgcn_mfma_f32_16x16x32_bf16(bfv[sf], af[of], acc[of][sf], 0, 0, 0);
                }
        }
        if (pf) { writeX(cur ^ 1); writeW(cur ^ 1); }   // back buffers: no conflict
        __syncthreads();                                 // single barrier per iter
        cur ^= 1;
    }

    if constexpr (EPI == 7) {
        // fused qkv head-norm. oc-block == one (t,h): t = oc0>>8, h = (oc0>>6)&3.
        int t_ = oc0 >> 8;
        int h_ = (oc0 >> 6) & 3;
        _Float16* qk16 = (_Float16*)out_h;
#pragma unroll
        for (int sf = 0; sf < 4; sf++) {
            int sp = spb * 512 + (2 * wv + (sf >> 1)) * 32 + (sf & 1) * 16 + l15;
            float ss = 0.f;
#pragma unroll
            for (int of = 0; of < 4; of++)
#pragma unroll
                for (int r = 0; r < 4; r++) ss += acc[of][sf][r] * acc[of][sf][r];
            ss += __shfl_xor(ss, 16);
            ss += __shfl_xor(ss, 32);
            float inv = 1.0f / (EPSV + sqrtf(ss) * 0.125f);
            if (t_ == 0) inv *= 0.18033688f;     // fold (1/8)*log2(e) into Q
            if (t_ < 2) {
#pragma unroll
                for (int of = 0; of < 4; of++) {
                    int ocb = oc0 + of * 16 + g * 4;
                    store_f16x4(&qk16[((size_t)n * 1024 + sp) * 768 + ocb],
                                acc[of][sf][0] * inv, acc[of][sf][1] * inv,
                                acc[of][sf][2] * inv, acc[of][sf][3] * inv);
                }
            } else {
#pragma unroll
                for (int of = 0; of < 4; of++)
#pragma unroll
                    for (int r = 0; r < 4; r++) {
                        int c = (of * 16 + g * 4 + r) & 63;
                        vt_out[((size_t)((n * 4 + h_) * 64 + c)) * 1024 + sp] =
                            (_Float16)(acc[of][sf][r] * inv);
                    }
            }
        }
        return;
    }

#pragma unroll
    for (int of = 0; of < 4; of++)
#pragma unroll
        for (int sf = 0; sf < 4; sf++) {
            if constexpr (ORI == 1) {
                int sp = spb * 512 + (2 * wv + (sf >> 1)) * 32 + (sf & 1) * 16 + l15;
                int ocb = oc0 + of * 16 + g * 4;
                size_t a = ((size_t)n * 1024 + sp) * Cout + ocb;
                if constexpr (EPI == 1) {
                    float vv[4];
#pragma unroll
                    for (int r = 0; r < 4; r++) {
                        float t = acc[of][sf][r] * cvec[n * 256 + ocb + r];
                        vv[r] = t / (1.0f + __expf(-t)) * INV596;
                    }
                    store_bf4(&out_h[a], vv[0], vv[1], vv[2], vv[3]);
                } else if constexpr (EPI == 2) {
                    float4 xr = *(const float4*)&xres[a];
                    float v0 = WA * xr.x + WB * acc[of][sf][0];
                    float v1 = WA * xr.y + WB * acc[of][sf][1];
                    float v2 = WA * xr.z + WB * acc[of][sf][2];
                    float v3 = WA * xr.w + WB * acc[of][sf][3];
                    *(float4*)&out_f[a] = make_float4(v0, v1, v2, v3);
                    store_bf4(&out_h[a], v0, v1, v2, v3);
                }
            } else {
                int oc = oc0 + of * 16 + l15;
                int spw = spb * 512 + (2 * wv + (sf >> 1)) * 32 + (sf & 1) * 16 + g * 4;
                if constexpr (EPI == 6) {
                    float vv[4];
#pragma unroll
                    for (int r = 0; r < 4; r++) {
                        float xr = xres[((size_t)n * 1024 + spw + r) * 256 + oc];
                        float vo = WA * xr + WB * acc[of][sf][r];
                        vv[r] = fminf(fmaxf(vo, -256.f), 256.f);
                    }
                    *(float4*)&out_f[((size_t)n * 256 + oc) * 1024 + spw] =
                        make_float4(vv[0], vv[1], vv[2], vv[3]);
                }
            }
        }
}

// ---------------- MFMA flash attention v6 (unchanged) ----------------
__device__ inline int swz64(int row, int c8) { return row * 64 + ((c8 ^ (row & 7)) << 3); }

__global__ __launch_bounds__(512) void attn_mfma(const _Float16* __restrict__ qkv3,
                                                 const _Float16* __restrict__ vt,
                                                 __hip_bfloat16* __restrict__ outp) {
    int lin = blockIdx.x + 4 * (blockIdx.y + 4 * blockIdx.z);
    int swz = (lin & 7) * 64 + (lin >> 3);
    int qt = swz & 3;
    int W = swz >> 2;
    int h = W & 3, n = W >> 2;

    __shared__ __align__(16) _Float16 Ks[2][64 * 64];
    __shared__ __align__(16) _Float16 Vs[2][64 * 64];
    __shared__ __align__(16) _Float16 Ps[8][32 * 64];
    int tid = threadIdx.x;
    int lane = tid & 63, wv = tid >> 6;
    int l15 = lane & 15, g = lane >> 4;

    f16x8 qreg[2][2];
#pragma unroll
    for (int nf = 0; nf < 2; nf++)
#pragma unroll
        for (int cc = 0; cc < 2; cc++)
            qreg[nf][cc] = *(const f16x8*)&qkv3[
                ((size_t)(n * 1024 + qt * 256 + wv * 32 + nf * 16 + l15)) * 768 + h * 64 + cc * 32 + g * 8];

    f16x8 kp, vp;
    int krow = tid >> 3, kslot = tid & 7;
    auto loadKV = [&](int kt) {
        kp = *(const f16x8*)&qkv3[((size_t)(n * 1024 + kt * 64 + krow)) * 768 + 256 + h * 64 + kslot * 8];
        vp = *(const f16x8*)&vt[((size_t)((n * 4 + h) * 64 + krow)) * 1024 + kt * 64 + kslot * 8];
    };
    int kdst = swz64(krow, kslot);
    auto writeKV = [&](int b) {
        *(f16x8*)&Ks[b][kdst] = kp;
        *(f16x8*)&Vs[b][kdst] = vp;
    };

    f32x4 acc_o[2][4];
    const f32x4 z4 = {0.f, 0.f, 0.f, 0.f};
#pragma unroll
    for (int a = 0; a < 2; a++)
#pragma unroll
        for (int b = 0; b < 4; b++) acc_o[a][b] = z4;
    float l_run[2] = {0.f, 0.f};

    loadKV(0); writeKV(0);
    __syncthreads();

    for (int kt = 0; kt < 16; kt++) {
        int cur = kt & 1;
        if (kt < 15) loadKV(kt + 1);

        f32x4 accs[4][2];
#pragma unroll
        for (int a = 0; a < 4; a++)
#pragma unroll
            for (int b = 0; b < 2; b++) accs[a][b] = z4;
        __builtin_amdgcn_s_setprio(1);
#pragma unroll
        for (int cc = 0; cc < 2; cc++) {
            f16x8 kf[4];
#pragma unroll
            for (int mf = 0; mf < 4; mf++)
                kf[mf] = *(const f16x8*)&Ks[cur][swz64(mf * 16 + l15, cc * 4 + g)];
#pragma unroll
            for (int mf = 0; mf < 4; mf++)
#pragma unroll
                for (int nf = 0; nf < 2; nf++)
                    accs[mf][nf] = __builtin_amdgcn_mfma_f32_16x16x32_f16(kf[mf], qreg[nf][cc], accs[mf][nf], 0, 0, 0);
        }
        __builtin_amdgcn_s_setprio(0);

#pragma unroll
        for (int nf = 0; nf < 2; nf++) {
            int q = nf * 16 + l15;
            float rs = 0.f;
#pragma unroll
            for (int mf = 0; mf < 4; mf++) {
                float p0 = __builtin_amdgcn_exp2f(accs[mf][nf][0]);
                float p1 = __builtin_amdgcn_exp2f(accs[mf][nf][1]);
                float p2 = __builtin_amdgcn_exp2f(accs[mf][nf][2]);
                float p3 = __builtin_amdgcn_exp2f(accs[mf][nf][3]);
                rs += (p0 + p1) + (p2 + p3);
                unsigned w0 = __builtin_bit_cast(unsigned, __builtin_amdgcn_cvt_pkrtz(p0, p1));
                unsigned w1 = __builtin_bit_cast(unsigned, __builtin_amdgcn_cvt_pkrtz(p2, p3));
                int elem = swz64(q, mf * 2 + (g >> 1)) + (g & 1) * 4;
                *(uint2*)&Ps[wv][elem] = make_uint2(w0, w1);
            }
            l_run[nf] += rs;
        }

        __builtin_amdgcn_s_setprio(1);
#pragma unroll
        for (int kc = 0; kc < 2; kc++) {
            f16x8 pf[2], vf[4];
#pragma unroll
            for (int mf2 = 0; mf2 < 2; mf2++)
                pf[mf2] = *(const f16x8*)&Ps[wv][swz64(mf2 * 16 + l15, kc * 4 + g)];
#pragma unroll
            for (int nf2 = 0; nf2 < 4; nf2++)
                vf[nf2] = *(const f16x8*)&Vs[cur][swz64(nf2 * 16 + l15, kc * 4 + g)];
#pragma unroll
            for (int mf2 = 0; mf2 < 2; mf2++)
#pragma unroll
                for (int nf2 = 0; nf2 < 4; nf2++)
                    acc_o[mf2][nf2] = __builtin_amdgcn_mfma_f32_16x16x32_f16(pf[mf2], vf[nf2], acc_o[mf2][nf2], 0, 0, 0);
        }
        __builtin_amdgcn_s_setprio(0);

        if (kt < 15) writeKV(cur ^ 1);
        __syncthreads();
    }

#pragma unroll
    for (int nf = 0; nf < 2; nf++) {
        float l = l_run[nf];
        l += __shfl_xor(l, 16);
        l += __shfl_xor(l, 32);
        float ilr = 1.0f / l;
#pragma unroll
        for (int r = 0; r < 4; r++) {
            float il = __shfl(ilr, g * 4 + r);
            int q = qt * 256 + wv * 32 + nf * 16 + g * 4 + r;
#pragma unroll
            for (int nf2 = 0; nf2 < 4; nf2++)
                outp[((size_t)(n * 1024 + q)) * 256 + h * 64 + nf2 * 16 + l15] =
                    __float2bfloat16(acc_o[nf][nf2][r] * il);
        }
    }
}

extern "C" void kernel_launch(void* const* d_in, const int* in_sizes, int n_in,
                              void* d_out, int out_size, void* d_ws, size_t ws_size,
                              hipStream_t stream) {
    (void)in_sizes; (void)n_in; (void)out_size; (void)ws_size;
    const float* x        = (const float*)d_in[0];
    const float* emb      = (const float*)d_in[1];
    const float* w_res0   = (const float*)d_in[2];
    const float* w_emb    = (const float*)d_in[3];
    const float* w_res1   = (const float*)d_in[4];
    const float* w_qkv    = (const float*)d_in[5];
    const float* w_proj   = (const float*)d_in[6];
    const float* emb_gain = (const float*)d_in[7];
    float* out = (float*)d_out;

    const size_t MB = 1048576;
    char* wsb = (char*)d_ws;
    float* X             = (float*)wsb;
    __hip_bfloat16* A1h  = (__hip_bfloat16*)(wsb + 32 * MB);
    __hip_bfloat16* A2h  = (__hip_bfloat16*)(wsb + 48 * MB);
    __hip_bfloat16* QKV3 = A2h;
    _Float16* Vt         = (_Float16*)d_out;
    char* wp = wsb + 96 * MB;
    __hip_bfloat16* W0B = (__hip_bfloat16*)wp;              wp += 9 * 256 * 256 * 2;
    __hip_bfloat16* W1B = (__hip_bfloat16*)wp;              wp += 9 * 256 * 256 * 2;
    __hip_bfloat16* WQB = (__hip_bfloat16*)wp;              wp += 768 * 256 * 2;
    __hip_bfloat16* WPB = (__hip_bfloat16*)wp;              wp += 256 * 256 * 2;
    float* CC           = (float*)wp;

    prep_all<<<2816, 256, 0, stream>>>(x, emb, w_res0, w_res1, w_qkv, w_proj, w_emb,
                                       emb_gain, W0B, W1B, WQB, WPB, CC, X, A1h);

    convmfma<3, 1, 1, 4><<<dim3(4, 2, 32), 512, 0, stream>>>(A1h, W0B, A2h, nullptr, nullptr, nullptr, CC, 256, 256);
    convmfma<3, 1, 2, 4><<<dim3(4, 2, 32), 512, 0, stream>>>(A2h, W1B, A1h, X, X, nullptr, nullptr, 256, 256);
    convmfma<1, 1, 7, 12><<<dim3(12, 2, 32), 512, 0, stream>>>(A1h, WQB, QKV3, nullptr, nullptr, Vt, nullptr, 256, 768);
    attn_mfma<<<dim3(4, 4, 32), 512, 0, stream>>>((const _Float16*)QKV3, Vt, A1h);
    convmfma<1, 2, 6, 4><<<dim3(4, 2, 32), 512, 0, stream>>>(A1h, WPB, nullptr, out, X, nullptr, nullptr, 256, 256);
}

// Round 21
// 218.558 us; speedup vs baseline: 1.0227x; 1.0227x over previous
//
#include <hip/hip_runtime.h>
#include <hip/hip_bf16.h>
#include <math.h>

#define EPSV 1e-4f
#define WA 0.91914503f          // 0.7 / sqrt(0.58)
#define WB 0.39392215f          // 0.3 / sqrt(0.58)
#define INV596 1.6778523f       // 1/0.596

typedef __bf16 bf16x8 __attribute__((ext_vector_type(8)));
typedef short  s16x8  __attribute__((ext_vector_type(8)));
typedef float  f32x4  __attribute__((ext_vector_type(4)));
typedef _Float16 f16x8 __attribute__((ext_vector_type(8)));

__device__ inline bf16x8 bzero8() { s16x8 z = 0; return __builtin_bit_cast(bf16x8, z); }

__device__ inline void store_bf4(__hip_bfloat16* p, float a, float b, float c, float d) {
    __hip_bfloat16 t[4];
    t[0] = __float2bfloat16(a); t[1] = __float2bfloat16(b);
    t[2] = __float2bfloat16(c); t[3] = __float2bfloat16(d);
    *(short4*)p = *(short4*)t;
}

__device__ inline void store_f16x4(_Float16* p, float a, float b, float c, float d) {
    _Float16 t[4];
    t[0] = (_Float16)a; t[1] = (_Float16)b; t[2] = (_Float16)c; t[3] = (_Float16)d;
    *(uint2*)p = *(uint2*)t;
}

// ---------------- prep: all weight norms + emb->c + pixnorm, one dispatch ----------------
// blocks [0,256): res0 | [256,512): res1 | [512,1280): qkv permuted |
// [1280,1536): proj | [1536,1792): emb row norm + c | [1792,2816): pixnorm
__global__ __launch_bounds__(256) void prep_all(
        const float* __restrict__ x, const float* __restrict__ emb,
        const float* __restrict__ w_res0, const float* __restrict__ w_res1,
        const float* __restrict__ w_qkv, const float* __restrict__ w_proj,
        const float* __restrict__ w_emb, const float* __restrict__ emb_gain,
        __hip_bfloat16* __restrict__ W0B, __hip_bfloat16* __restrict__ W1B,
        __hip_bfloat16* __restrict__ WQB, __hip_bfloat16* __restrict__ WPB,
        float* __restrict__ CC, float* __restrict__ Xn,
        __hip_bfloat16* __restrict__ Ah) {
    __shared__ float sdata[4];
    int b = blockIdx.x;
    int tid = threadIdx.x;
    int wid = tid >> 6, lane = tid & 63;

    if (b < 512) {                       // 3x3 conv weight norm
        int oc = b & 255;
        const float* row = ((b < 256) ? w_res0 : w_res1) + (size_t)oc * 2304;
        __hip_bfloat16* wb = (b < 256) ? W0B : W1B;
        float ss = 0.f;
        for (int i = tid; i < 2304; i += 256) { float v = row[i]; ss += v * v; }
#pragma unroll
        for (int m = 32; m >= 1; m >>= 1) ss += __shfl_xor(ss, m);
        if (lane == 0) sdata[wid] = ss;
        __syncthreads();
        float tot = sdata[0] + sdata[1] + sdata[2] + sdata[3];
        float s = (1.0f / 48.0f) / (EPSV + sqrtf(tot) * (1.0f / 48.0f));
        for (int i = tid; i < 2304; i += 256) {
            int ic = i / 9, tap = i - ic * 9;
            wb[((size_t)tap * 256 + oc) * 256 + ic] = __float2bfloat16(row[i] * s);
        }
    } else if (b < 1536) {               // 1x1 conv weight norm (qkv permuted / proj)
        bool isq = (b < 1280);
        int oc = isq ? (b - 512) : (b - 1280);
        const float* row = (isq ? w_qkv : w_proj) + (size_t)oc * 256;
        float v0 = row[tid];
        float ss = v0 * v0;
#pragma unroll
        for (int m = 32; m >= 1; m >>= 1) ss += __shfl_xor(ss, m);
        if (lane == 0) sdata[wid] = ss;
        __syncthreads();
        float tot = sdata[0] + sdata[1] + sdata[2] + sdata[3];
        float s = 0.0625f / (EPSV + sqrtf(tot) * 0.0625f);
        if (isq) {
            int h = oc / 192, rem = oc - h * 192;
            int c = rem / 3, t = rem - c * 3;
            int newoc = t * 256 + h * 64 + c;
            WQB[(size_t)newoc * 256 + tid] = __float2bfloat16(v0 * s);
        } else {
            WPB[(size_t)oc * 256 + tid] = __float2bfloat16(v0 * s);
        }
    } else if (b < 1792) {               // emb weight row r: norm + c[n][r] directly
        int r = b - 1536;
        const float* row = w_emb + (size_t)r * 768;
        float ss = 0.f;
        for (int i = tid; i < 768; i += 256) { float v = row[i]; ss += v * v; }
#pragma unroll
        for (int m = 32; m >= 1; m >>= 1) ss += __shfl_xor(ss, m);
        if (lane == 0) sdata[wid] = ss;
        __syncthreads();
        float tot = sdata[0] + sdata[1] + sdata[2] + sdata[3];
        float g = emb_gain[0];
        float s = g * 0.036084392f / (EPSV + sqrtf(tot) * 0.036084392f);
        __shared__ float rowS[768];
        for (int i = tid; i < 768; i += 256) rowS[i] = row[i] * s;
        __syncthreads();
        int n_ = tid >> 3, k0 = tid & 7;
        float p = 0.f;
        for (int k = k0; k < 768; k += 8) p += emb[n_ * 768 + k] * rowS[k];
        p += __shfl_xor(p, 1);
        p += __shfl_xor(p, 2);
        p += __shfl_xor(p, 4);
        if (k0 == 0) CC[n_ * 256 + r] = p + 1.0f;
    } else {                             // pixnorm: idx -> (n, sp-block)
        int idx = b - 1792;
        int n = idx >> 5;
        int sp = (idx & 31) * 32 + (tid & 31);
        int cg = tid >> 5;
        const float* xb = x + (size_t)n * 262144 + ((size_t)cg << 15) + sp;
        float v[32];
        float ss = 0.f;
#pragma unroll
        for (int i = 0; i < 32; i++) {
            v[i] = xb[(size_t)i << 10];
            ss += v[i] * v[i];
        }
        __shared__ float red[8][33];
        red[cg][tid & 31] = ss;
        __syncthreads();
        float tot = 0.f;
#pragma unroll
        for (int j = 0; j < 8; j++) tot += red[j][tid & 31];
        float inv = 1.0f / (EPSV + sqrtf(tot) * 0.0625f);
        float* xo = Xn + ((size_t)n * 1024 + sp) * 256 + cg * 32;
        __hip_bfloat16* ao = Ah + ((size_t)n * 1024 + sp) * 256 + cg * 32;
#pragma unroll
        for (int i = 0; i < 32; i += 4) {
            float a0 = v[i] * inv, a1 = v[i+1] * inv, a2 = v[i+2] * inv, a3 = v[i+3] * inv;
            *(float4*)&xo[i] = make_float4(a0, a1, a2, a3);
            float s0 = a0 / (1.0f + __expf(-a0)) * INV596;
            float s1 = a1 / (1.0f + __expf(-a1)) * INV596;
            float s2 = a2 / (1.0f + __expf(-a2)) * INV596;
            float s3 = a3 / (1.0f + __expf(-a3)) * INV596;
            store_bf4(&ao[i], s0, s1, s2, s3);
        }
    }
}

// ---------------- MFMA implicit-GEMM conv (R18 structure) ----------------
// EPI 1: silu(acc*c) bf16 NHWC | 2: mp_sum f32+bf16 NHWC | 6: mp_sum+clip f32 NCHW
// EPI 7: fused qkv head-norm: Q/K f16 in place (+log2e fold on Q), V -> Vt f16.
template<int KS, int ORI, int EPI, int GX>
__global__ __launch_bounds__(256) void convmfma(
        const __hip_bfloat16* __restrict__ xin,
        const __hip_bfloat16* __restrict__ wb,
        __hip_bfloat16* __restrict__ out_h,
        float* __restrict__ out_f,
        const float* __restrict__ xres,
        _Float16* __restrict__ vt_out,
        const float* __restrict__ cvec,
        int Cin, int Cout) {
    constexpr int TAPS = KS * KS;
    constexpr int RRD = 8 + KS - 1;
    constexpr int CCD = 32 + KS - 1;
    constexpr int HLO = KS / 2;
    constexpr int NX = (RRD * 128) / 256;
    __shared__ __align__(16) __hip_bfloat16 Xl[RRD * CCD * 32];
    __shared__ __align__(16) __hip_bfloat16 Wl[TAPS * 64 * 32];

    auto xoff = [](int rr, int cc, int gran) {
        int rowl = rr * CCD + cc;
        return rowl * 32 + ((gran ^ ((rowl >> 1) & 3)) << 3);
    };
    auto woff = [](int tap, int oc, int gran) {
        int rowl = tap * 64 + oc;
        return rowl * 32 + ((gran ^ ((rowl >> 1) & 3)) << 3);
    };

    int lin = blockIdx.x + GX * (blockIdx.y + 4 * blockIdx.z);
    constexpr int NBLK = GX * 4 * 32;
    constexpr int CPX = NBLK >> 3;
    int swz = (lin & 7) * CPX + (lin >> 3);
    int oc0 = (swz % GX) * 64;
    int W = swz / GX;
    int spblk = W & 3;
    int n = W >> 2;

    int tid = threadIdx.x;
    int r0 = spblk * 8;
    int lane = tid & 63, wv = tid >> 6;
    int l15 = lane & 15, g = lane >> 4;

    if (KS == 3) {
        if (tid < RRD * 2 * 4) {
            int rr = tid >> 3;
            int side = (tid >> 2) & 1;
            int slot = tid & 3;
            *(bf16x8*)&Xl[xoff(rr, side ? (CCD - 1) : 0, slot)] = bzero8();
        }
    }

    bf16x8 xp[NX];
    bf16x8 wpf[TAPS];
    auto loadX = [&](int ch) {
#pragma unroll
        for (int u = 0; u < NX; u++) {
            int f = tid + u * 256;
            int rr = f >> 7, rem = f & 127;
            int cc = rem >> 2, slot = rem & 3;
            int gr = r0 + rr - HLO;
            bf16x8 v = bzero8();
            if ((unsigned)gr < 32u)
                v = *(const bf16x8*)&xin[((size_t)n * 1024 + gr * 32 + cc) * Cin + ch * 32 + slot * 8];
            xp[u] = v;
        }
    };
    auto writeX = [&]() {
#pragma unroll
        for (int u = 0; u < NX; u++) {
            int f = tid + u * 256;
            int rr = f >> 7, rem = f & 127;
            int cc = rem >> 2, slot = rem & 3;
            *(bf16x8*)&Xl[xoff(rr, cc + HLO, slot)] = xp[u];
        }
    };
    auto loadW = [&](int ch) {
#pragma unroll
        for (int u = 0; u < TAPS; u++) {
            int f = tid + u * 256;
            int tap = f >> 8, rem = f & 255;
            int oc = rem >> 2, slot = rem & 3;
            wpf[u] = *(const bf16x8*)&wb[((size_t)tap * Cout + oc0 + oc) * Cin + ch * 32 + slot * 8];
        }
    };
    auto writeW = [&]() {
#pragma unroll
        for (int u = 0; u < TAPS; u++) {
            int f = tid + u * 256;
            int tap = f >> 8, rem = f & 255;
            int oc = rem >> 2, slot = rem & 3;
            *(bf16x8*)&Wl[woff(tap, oc, slot)] = wpf[u];
        }
    };

    f32x4 acc[4][4];
    const f32x4 z4 = {0.f, 0.f, 0.f, 0.f};
#pragma unroll
    for (int a = 0; a < 4; a++)
#pragma unroll
        for (int b = 0; b < 4; b++) acc[a][b] = z4;

    int nch = Cin >> 5;
    loadX(0); loadW(0);
    writeX(); writeW();
    __syncthreads();

    for (int ch = 0; ch < nch; ++ch) {
        bool pf = (ch + 1 < nch);
        if (pf) { loadX(ch + 1); loadW(ch + 1); }
        if constexpr (KS == 3) {
#pragma unroll
            for (int dx = 0; dx < 3; dx++) {
                bf16x8 xv[4][2];
#pragma unroll
                for (int r = 0; r < 4; r++)
#pragma unroll
                    for (int b = 0; b < 2; b++)
                        xv[r][b] = *(const bf16x8*)&Xl[xoff(2 * wv + r, b * 16 + l15 + dx, g)];
#pragma unroll
                for (int dy = 0; dy < 3; dy++) {
                    int tap = dy * 3 + dx;
                    bf16x8 af[4];
#pragma unroll
                    for (int of = 0; of < 4; of++)
                        af[of] = *(const bf16x8*)&Wl[woff(tap, of * 16 + l15, g)];
#pragma unroll
                    for (int of = 0; of < 4; of++)
#pragma unroll
                        for (int sf = 0; sf < 4; sf++) {
                            if (ORI == 1)
                                acc[of][sf] = __builtin_amdgcn_mfma_f32_16x16x32_bf16(af[of], xv[(sf >> 1) + dy][sf & 1], acc[of][sf], 0, 0, 0);
                            else
                                acc[of][sf] = __builtin_amdgcn_mfma_f32_16x16x32_bf16(xv[(sf >> 1) + dy][sf & 1], af[of], acc[of][sf], 0, 0, 0);
                        }
                }
            }
        } else {
#pragma unroll
            for (int tap = 0; tap < TAPS; ++tap) {
                bf16x8 af[4], bfv[4];
#pragma unroll
                for (int of = 0; of < 4; of++)
                    af[of] = *(const bf16x8*)&Wl[woff(tap, of * 16 + l15, g)];
#pragma unroll
                for (int sf = 0; sf < 4; sf++) {
                    int rr = 2 * wv + (sf >> 1);
                    int cc2 = (sf & 1) * 16 + l15;
                    bfv[sf] = *(const bf16x8*)&Xl[xoff(rr, cc2, g)];
                }
#pragma unroll
                for (int of = 0; of < 4; of++)
#pragma unroll
                    for (int sf = 0; sf < 4; sf++) {
                        if (ORI == 1)
                            acc[of][sf] = __builtin_amdgcn_mfma_f32_16x16x32_bf16(af[of], bfv[sf], acc[of][sf], 0, 0, 0);
                        else
                            acc[of][sf] = __builtin_amdgcn_mfma_f32_16x16x32_bf16(bfv[sf], af[of], acc[of][sf], 0, 0, 0);
                    }
            }
        }
        __syncthreads();
        if (pf) { writeX(); writeW(); __syncthreads(); }
    }

    if constexpr (EPI == 7) {
        // fused qkv head-norm. oc-block == one (t,h): t = oc0>>8, h = (oc0>>6)&3.
        int t_ = oc0 >> 8;
        int h_ = (oc0 >> 6) & 3;
        _Float16* qk16 = (_Float16*)out_h;
#pragma unroll
        for (int sf = 0; sf < 4; sf++) {
            int sp = spblk * 256 + (2 * wv + (sf >> 1)) * 32 + (sf & 1) * 16 + l15;
            float ss = 0.f;
#pragma unroll
            for (int of = 0; of < 4; of++)
#pragma unroll
                for (int r = 0; r < 4; r++) ss += acc[of][sf][r] * acc[of][sf][r];
            ss += __shfl_xor(ss, 16);
            ss += __shfl_xor(ss, 32);
            float inv = 1.0f / (EPSV + sqrtf(ss) * 0.125f);
            if (t_ == 0) inv *= 0.18033688f;     // fold (1/8)*log2(e) into Q
            if (t_ < 2) {
#pragma unroll
                for (int of = 0; of < 4; of++) {
                    int ocb = oc0 + of * 16 + g * 4;
                    store_f16x4(&qk16[((size_t)n * 1024 + sp) * 768 + ocb],
                                acc[of][sf][0] * inv, acc[of][sf][1] * inv,
                                acc[of][sf][2] * inv, acc[of][sf][3] * inv);
                }
            } else {
#pragma unroll
                for (int of = 0; of < 4; of++)
#pragma unroll
                    for (int r = 0; r < 4; r++) {
                        int c = (of * 16 + g * 4 + r) & 63;
                        vt_out[((size_t)((n * 4 + h_) * 64 + c)) * 1024 + sp] =
                            (_Float16)(acc[of][sf][r] * inv);
                    }
            }
        }
        return;
    }

#pragma unroll
    for (int of = 0; of < 4; of++)
#pragma unroll
        for (int sf = 0; sf < 4; sf++) {
            if constexpr (ORI == 1) {
                int row_l = 2 * wv + (sf >> 1);
                int col = (sf & 1) * 16 + l15;
                int sp = spblk * 256 + row_l * 32 + col;
                int ocb = oc0 + of * 16 + g * 4;
                size_t a = ((size_t)n * 1024 + sp) * Cout + ocb;
                if constexpr (EPI == 1) {
                    float vv[4];
#pragma unroll
                    for (int r = 0; r < 4; r++) {
                        float t = acc[of][sf][r] * cvec[n * 256 + ocb + r];
                        vv[r] = t / (1.0f + __expf(-t)) * INV596;
                    }
                    store_bf4(&out_h[a], vv[0], vv[1], vv[2], vv[3]);
                } else if constexpr (EPI == 2) {
                    float4 xr = *(const float4*)&xres[a];
                    float v0 = WA * xr.x + WB * acc[of][sf][0];
                    float v1 = WA * xr.y + WB * acc[of][sf][1];
                    float v2 = WA * xr.z + WB * acc[of][sf][2];
                    float v3 = WA * xr.w + WB * acc[of][sf][3];
                    *(float4*)&out_f[a] = make_float4(v0, v1, v2, v3);
                    store_bf4(&out_h[a], v0, v1, v2, v3);   // out_h = bf16 mirror
                }
            } else {
                int oc = oc0 + of * 16 + l15;
                int spb = spblk * 256 + (2 * wv + (sf >> 1)) * 32 + (sf & 1) * 16 + g * 4;
                if constexpr (EPI == 6) {
                    float vv[4];
#pragma unroll
                    for (int r = 0; r < 4; r++) {
                        float xr = xres[((size_t)n * 1024 + spb + r) * 256 + oc];
                        float vo = WA * xr + WB * acc[of][sf][r];
                        vv[r] = fminf(fmaxf(vo, -256.f), 256.f);
                    }
                    *(float4*)&out_f[((size_t)n * 256 + oc) * 1024 + spb] =
                        make_float4(vv[0], vv[1], vv[2], vv[3]);
                }
            }
        }
}

// ---------------- MFMA flash attention v6 ----------------
__device__ inline int swz64(int row, int c8) { return row * 64 + ((c8 ^ (row & 7)) << 3); }

__global__ __launch_bounds__(512) void attn_mfma(const _Float16* __restrict__ qkv3,
                                                 const _Float16* __restrict__ vt,
                                                 __hip_bfloat16* __restrict__ outp) {
    int lin = blockIdx.x + 4 * (blockIdx.y + 4 * blockIdx.z);
    int swz = (lin & 7) * 64 + (lin >> 3);
    int qt = swz & 3;
    int W = swz >> 2;
    int h = W & 3, n = W >> 2;

    __shared__ __align__(16) _Float16 Ks[2][64 * 64];
    __shared__ __align__(16) _Float16 Vs[2][64 * 64];
    __shared__ __align__(16) _Float16 Ps[8][32 * 64];
    int tid = threadIdx.x;
    int lane = tid & 63, wv = tid >> 6;
    int l15 = lane & 15, g = lane >> 4;

    f16x8 qreg[2][2];
#pragma unroll
    for (int nf = 0; nf < 2; nf++)
#pragma unroll
        for (int cc = 0; cc < 2; cc++)
            qreg[nf][cc] = *(const f16x8*)&qkv3[
                ((size_t)(n * 1024 + qt * 256 + wv * 32 + nf * 16 + l15)) * 768 + h * 64 + cc * 32 + g * 8];

    f16x8 kp, vp;
    int krow = tid >> 3, kslot = tid & 7;
    auto loadKV = [&](int kt) {
        kp = *(const f16x8*)&qkv3[((size_t)(n * 1024 + kt * 64 + krow)) * 768 + 256 + h * 64 + kslot * 8];
        vp = *(const f16x8*)&vt[((size_t)((n * 4 + h) * 64 + krow)) * 1024 + kt * 64 + kslot * 8];
    };
    int kdst = swz64(krow, kslot);
    auto writeKV = [&](int b) {
        *(f16x8*)&Ks[b][kdst] = kp;
        *(f16x8*)&Vs[b][kdst] = vp;
    };

    f32x4 acc_o[2][4];
    const f32x4 z4 = {0.f, 0.f, 0.f, 0.f};
#pragma unroll
    for (int a = 0; a < 2; a++)
#pragma unroll
        for (int b = 0; b < 4; b++) acc_o[a][b] = z4;
    float l_run[2] = {0.f, 0.f};

    loadKV(0); writeKV(0);
    __syncthreads();

    for (int kt = 0; kt < 16; kt++) {
        int cur = kt & 1;
        if (kt < 15) loadKV(kt + 1);

        f32x4 accs[4][2];
#pragma unroll
        for (int a = 0; a < 4; a++)
#pragma unroll
            for (int b = 0; b < 2; b++) accs[a][b] = z4;
        __builtin_amdgcn_s_setprio(1);
#pragma unroll
        for (int cc = 0; cc < 2; cc++) {
            f16x8 kf[4];
#pragma unroll
            for (int mf = 0; mf < 4; mf++)
                kf[mf] = *(const f16x8*)&Ks[cur][swz64(mf * 16 + l15, cc * 4 + g)];
#pragma unroll
            for (int mf = 0; mf < 4; mf++)
#pragma unroll
                for (int nf = 0; nf < 2; nf++)
                    accs[mf][nf] = __builtin_amdgcn_mfma_f32_16x16x32_f16(kf[mf], qreg[nf][cc], accs[mf][nf], 0, 0, 0);
        }
        __builtin_amdgcn_s_setprio(0);

#pragma unroll
        for (int nf = 0; nf < 2; nf++) {
            int q = nf * 16 + l15;
            float rs = 0.f;
#pragma unroll
            for (int mf = 0; mf < 4; mf++) {
                float p0 = __builtin_amdgcn_exp2f(accs[mf][nf][0]);
                float p1 = __builtin_amdgcn_exp2f(accs[mf][nf][1]);
                float p2 = __builtin_amdgcn_exp2f(accs[mf][nf][2]);
                float p3 = __builtin_amdgcn_exp2f(accs[mf][nf][3]);
                rs += (p0 + p1) + (p2 + p3);
                unsigned w0 = __builtin_bit_cast(unsigned, __builtin_amdgcn_cvt_pkrtz(p0, p1));
                unsigned w1 = __builtin_bit_cast(unsigned, __builtin_amdgcn_cvt_pkrtz(p2, p3));
                int elem = swz64(q, mf * 2 + (g >> 1)) + (g & 1) * 4;
                *(uint2*)&Ps[wv][elem] = make_uint2(w0, w1);
            }
            l_run[nf] += rs;
        }

        __builtin_amdgcn_s_setprio(1);
#pragma unroll
        for (int kc = 0; kc < 2; kc++) {
            f16x8 pf[2], vf[4];
#pragma unroll
            for (int mf2 = 0; mf2 < 2; mf2++)
                pf[mf2] = *(const f16x8*)&Ps[wv][swz64(mf2 * 16 + l15, kc * 4 + g)];
#pragma unroll
            for (int nf2 = 0; nf2 < 4; nf2++)
                vf[nf2] = *(const f16x8*)&Vs[cur][swz64(nf2 * 16 + l15, kc * 4 + g)];
#pragma unroll
            for (int mf2 = 0; mf2 < 2; mf2++)
#pragma unroll
                for (int nf2 = 0; nf2 < 4; nf2++)
                    acc_o[mf2][nf2] = __builtin_amdgcn_mfma_f32_16x16x32_f16(pf[mf2], vf[nf2], acc_o[mf2][nf2], 0, 0, 0);
        }
        __builtin_amdgcn_s_setprio(0);

        if (kt < 15) writeKV(cur ^ 1);
        __syncthreads();
    }

#pragma unroll
    for (int nf = 0; nf < 2; nf++) {
        float l = l_run[nf];
        l += __shfl_xor(l, 16);
        l += __shfl_xor(l, 32);
        float ilr = 1.0f / l;
#pragma unroll
        for (int r = 0; r < 4; r++) {
            float il = __shfl(ilr, g * 4 + r);
            int q = qt * 256 + wv * 32 + nf * 16 + g * 4 + r;
#pragma unroll
            for (int nf2 = 0; nf2 < 4; nf2++)
                outp[((size_t)(n * 1024 + q)) * 256 + h * 64 + nf2 * 16 + l15] =
                    __float2bfloat16(acc_o[nf][nf2][r] * il);
        }
    }
}

extern "C" void kernel_launch(void* const* d_in, const int* in_sizes, int n_in,
                              void* d_out, int out_size, void* d_ws, size_t ws_size,
                              hipStream_t stream) {
    (void)in_sizes; (void)n_in; (void)out_size; (void)ws_size;
    const float* x        = (const float*)d_in[0];
    const float* emb      = (const float*)d_in[1];
    const float* w_res0   = (const float*)d_in[2];
    const float* w_emb    = (const float*)d_in[3];
    const float* w_res1   = (const float*)d_in[4];
    const float* w_qkv    = (const float*)d_in[5];
    const float* w_proj   = (const float*)d_in[6];
    const float* emb_gain = (const float*)d_in[7];
    float* out = (float*)d_out;

    const size_t MB = 1048576;
    char* wsb = (char*)d_ws;
    float* X             = (float*)wsb;
    __hip_bfloat16* A1h  = (__hip_bfloat16*)(wsb + 32 * MB);
    __hip_bfloat16* A2h  = (__hip_bfloat16*)(wsb + 48 * MB);
    __hip_bfloat16* QKV3 = A2h;
    _Float16* Vt         = (_Float16*)d_out;
    char* wp = wsb + 96 * MB;
    __hip_bfloat16* W0B = (__hip_bfloat16*)wp;              wp += 9 * 256 * 256 * 2;
    __hip_bfloat16* W1B = (__hip_bfloat16*)wp;              wp += 9 * 256 * 256 * 2;
    __hip_bfloat16* WQB = (__hip_bfloat16*)wp;              wp += 768 * 256 * 2;
    __hip_bfloat16* WPB = (__hip_bfloat16*)wp;              wp += 256 * 256 * 2;
    float* CC           = (float*)wp;

    prep_all<<<2816, 256, 0, stream>>>(x, emb, w_res0, w_res1, w_qkv, w_proj, w_emb,
                                       emb_gain, W0B, W1B, WQB, WPB, CC, X, A1h);

    convmfma<3, 1, 1, 4><<<dim3(4, 4, 32), 256, 0, stream>>>(A1h, W0B, A2h, nullptr, nullptr, nullptr, CC, 256, 256);
    convmfma<3, 1, 2, 4><<<dim3(4, 4, 32), 256, 0, stream>>>(A2h, W1B, A1h, X, X, nullptr, nullptr, 256, 256);
    // qkv 1x1 with fused head-norm epilogue: Q/K f16 into QKV3, V f16 -> Vt
    convmfma<1, 1, 7, 12><<<dim3(12, 4, 32), 256, 0, stream>>>(A1h, WQB, QKV3, nullptr, nullptr, Vt, nullptr, 256, 768);
    attn_mfma<<<dim3(4, 4, 32), 512, 0, stream>>>((const _Float16*)QKV3, Vt, A1h);
    convmfma<1, 2, 6, 4><<<dim3(4, 4, 32), 256, 0, stream>>>(A1h, WPB, nullptr, out, X, nullptr, nullptr, 256, 256);
}